// Round 5
// baseline (457.826 us; speedup 1.0000x reference)
//
#include <hip/hip_runtime.h>

typedef unsigned short u16;
typedef unsigned int   u32;

#define NB   32
#define CIN  512
#define CM   128
#define P2   256
#define HW   3136
#define HD   56

typedef __attribute__((ext_vector_type(8))) short           short8;
typedef __attribute__((ext_vector_type(8))) unsigned short  ushort8;
typedef __attribute__((ext_vector_type(4))) unsigned short  ushort4_t;
typedef __attribute__((ext_vector_type(4))) float           f32x4;
typedef __attribute__((ext_vector_type(2))) unsigned int    u32x2;

__device__ __forceinline__ float b2f(u16 u) {
    union { u32 i; float f; } v; v.i = ((u32)u) << 16; return v.f;
}
__device__ __forceinline__ u16 f2b(float f) {
    u32 u = __builtin_bit_cast(u32, f);
    u32 r = (u + 0x7fffu + ((u >> 16) & 1u)) >> 16;
    return (u16)r;
}

// ---------------- kernel 0: zero ym + convert weights f32 -> bf16 ----------------
__global__ __launch_bounds__(256) void init_kernel(const float* __restrict__ Wc,
                                                   const float* __restrict__ Wf,
                                                   u16* __restrict__ Wcb,
                                                   u16* __restrict__ Wfb,
                                                   float* __restrict__ ym) {
    int i = blockIdx.x * 256 + threadIdx.x;
    if (i < CM * CIN) { Wcb[i] = f2b(Wc[i]); return; }
    i -= CM * CIN;
    if (i < P2 * CM) { Wfb[i] = f2b(Wf[i]); return; }
    i -= P2 * CM;
    if (i < NB * CM) ym[i] = 0.f;
}

// ---------------- kernel 1: f = relu(Wconv @ x); ym[n,m] += sum_hw preact ----------------
// Swapped-operand MFMA: A = x-tile (hw is M-dim), B = W (m is N-dim).
// D layout: col(l15) = m, row(qa*4+r) = hw  -> 4 contiguous hw per lane -> 8B packed stores.
// Epilogue also accumulates sum_hw(acc) (pre-bias) into ym (2 shfl + 1 atomic per m):
// g = relu(ym/HW + bias) is computed later in dw, since Wconv@mean(x)+b == mean_hw(preact).
__global__ __launch_bounds__(256) void gemm1_kernel(
    const float* __restrict__ In,
    const u16* __restrict__ Wm, const float* __restrict__ bias,
    u16* __restrict__ Out, float* __restrict__ ym)
{
    __shared__ u16 ldsT[128 * 40];   // [hw_col][k32] transposed, stride 40 (16B-aligned b128 reads)

    const int n    = blockIdx.z;
    const int hw0  = blockIdx.x * 128;
    const int tid  = threadIdx.x;
    const int wave = tid >> 6, lane = tid & 63;
    const int wm   = (wave >> 1) * 64;   // wave m-offset
    const int wn   = (wave & 1) * 64;    // wave hw-offset
    const int qa   = lane >> 4;          // k-quad 0..3
    const int l15  = lane & 15;

    f32x4 acc[4][4] = {};                // [ht(hw)][nt(m)]

    // staging assignment: thread -> 2 k-rows x 8 hw-cols
    const int kpair = tid >> 4;            // 0..15 -> k rows 2*kpair, 2*kpair+1
    const int c0    = (tid & 15) * 8;      // hw col group
    const int hwc   = hw0 + c0;
    const bool cok  = (hwc < HW);

    for (int k0 = 0; k0 < CIN; k0 += 32) {
        __syncthreads();
        u32 pk[8];
        {
            f32x4 a0 = {0,0,0,0}, a1 = {0,0,0,0}, d0 = {0,0,0,0}, d1 = {0,0,0,0};
            if (cok) {
                const float* p0 = In + (size_t)n * CIN * HW
                                + (size_t)(k0 + kpair * 2) * HW + hwc;
                a0 = *(const f32x4*)p0;
                a1 = *(const f32x4*)(p0 + 4);
                d0 = *(const f32x4*)(p0 + HW);
                d1 = *(const f32x4*)(p0 + HW + 4);
            }
            float fa[8] = {a0[0],a0[1],a0[2],a0[3],a1[0],a1[1],a1[2],a1[3]};
            float fb[8] = {d0[0],d0[1],d0[2],d0[3],d1[0],d1[1],d1[2],d1[3]};
            #pragma unroll
            for (int e = 0; e < 8; ++e) {
                u32 ua = __builtin_bit_cast(u32, fa[e]) + 0x8000u;
                u32 ub = __builtin_bit_cast(u32, fb[e]) + 0x8000u;
                pk[e] = __builtin_amdgcn_perm(ub, ua, 0x07060302u);  // (hi16(ub)<<16)|hi16(ua)
            }
        }
        #pragma unroll
        for (int e = 0; e < 8; ++e)
            *(u32*)&ldsT[(c0 + e) * 40 + kpair * 2] = pk[e];
        __syncthreads();

        short8 b[4];
        #pragma unroll
        for (int nt = 0; nt < 4; ++nt) {
            int row = wm + nt * 16 + l15;
            b[nt] = *(const short8*)(Wm + (size_t)row * CIN + k0 + qa * 8);
        }
        #pragma unroll
        for (int ht = 0; ht < 4; ++ht) {
            short8 a = *(const short8*)&ldsT[(wn + ht * 16 + l15) * 40 + qa * 8];
            #pragma unroll
            for (int nt = 0; nt < 4; ++nt)
                acc[ht][nt] = __builtin_amdgcn_mfma_f32_16x16x32_bf16(a, b[nt], acc[ht][nt], 0, 0, 0);
        }
    }

    // epilogue: lane holds m = wm+nt*16+l15, hw = hw0+wn+ht*16+qa*4+r (contiguous)
    #pragma unroll
    for (int nt = 0; nt < 4; ++nt) {
        const int m = wm + nt * 16 + l15;
        const float bv = bias[m];
        float s = 0.f;
        #pragma unroll
        for (int ht = 0; ht < 4; ++ht) {
            f32x4 v = acc[ht][nt];
            s += v[0] + v[1] + v[2] + v[3];           // pre-bias sum for ym
            int hwb = hw0 + wn + ht * 16;
            if (hwb < HW) {
                float v0 = fmaxf(v[0] + bv, 0.f);
                float v1 = fmaxf(v[1] + bv, 0.f);
                float v2 = fmaxf(v[2] + bv, 0.f);
                float v3 = fmaxf(v[3] + bv, 0.f);
                u32x2 pkv;
                pkv.x = (u32)f2b(v0) | ((u32)f2b(v1) << 16);
                pkv.y = (u32)f2b(v2) | ((u32)f2b(v3) << 16);
                *(u32x2*)(Out + ((size_t)n * CM + m) * HW + hwb + qa * 4) = pkv;
            }
        }
        s += __shfl_xor(s, 16);
        s += __shfl_xor(s, 32);
        if (lane < 16) atomicAdd(&ym[n * CM + m], s);
    }
}

// ---------------- kernel 4: both depthwise branches (g computed inline) ----------------
#define PD 60
__global__ __launch_bounds__(256) void dw_kernel(
    const u16* __restrict__ f, const float* __restrict__ ym,
    const float* __restrict__ bc,
    const float* __restrict__ wk,  const float* __restrict__ bk,
    const float* __restrict__ wck, const float* __restrict__ bck,
    const float* __restrict__ wk2, const float* __restrict__ bk2,
    const float* __restrict__ wck2,const float* __restrict__ bck2,
    u16* __restrict__ o1, u16* __restrict__ o2)
{
    const int ncm = blockIdx.x;
    __shared__ float fpl[PD * PD];          // 14.4 KB, +-2 halo
    __shared__ float kc1[25], kc2[9];

    // phase A: zero only the halo strips (464 elems) + dynamic kernel coefficients
    {
        int t = threadIdx.x;
        if (t < 120) { fpl[t] = 0.f; fpl[58 * PD + t] = 0.f; }          // rows 0-1, 58-59
        else if (t < 232) {
            int u = t - 120;                   // 0..111 -> rows 2..57, 2 sides x 2 cols
            int r = 2 + (u >> 1), c = u & 1;
            fpl[r * PD + c]      = 0.f;        // cols 0,1
            fpl[r * PD + 58 + c] = 0.f;        // cols 58,59
        }
    }
    // g = relu(ym/HW + b_conv)
    const float gv = fmaxf(ym[ncm] * (1.0f / HW) + bc[ncm & (CM - 1)], 0.f);
    if (threadIdx.x < 25) {
        int t = threadIdx.x;
        kc1[t] = (gv * wk[t] + bk[t]) * wck[0] + bck[0];
    } else if (threadIdx.x >= 32 && threadIdx.x < 41) {
        int t = threadIdx.x - 32;
        kc2[t] = (gv * wk2[t] + bk2[t]) * wck2[0] + bck2[0];
    }
    __syncthreads();

    // phase B: fill interior (bf16 -> f32), 8B/lane (4 px; never crosses a row: 56%4==0)
    const size_t base = (size_t)ncm * HW;
    const u32x2* fp = (const u32x2*)(f + base);
    for (int i = threadIdx.x; i < HW / 4; i += 256) {
        u32x2 v = fp[i];
        int px = 4 * i;
        int h = px / HD, w = px - h * HD;   // w multiple of 4, w <= 52
        float* dst = &fpl[(h + 2) * PD + (w + 2)];
        dst[0] = b2f((u16)v.x);
        dst[1] = b2f((u16)(v.x >> 16));
        dst[2] = b2f((u16)v.y);
        dst[3] = b2f((u16)(v.y >> 16));
    }
    __syncthreads();

    // phase C: 8 px per unit; 7 groups x 56 rows = 392 units
    u32* o1p = (u32*)(o1 + base);
    u32* o2p = (u32*)(o2 + base);
    for (int u = threadIdx.x; u < 392; u += 256) {
        int h  = u / 7;
        int gq = u - h * 7;
        int w0 = gq * 8;
        float a1[8] = {}, a2[8] = {};
        #pragma unroll
        for (int di = 0; di < 5; ++di) {
            const float* row = &fpl[(h + di) * PD + w0];
            float r[12];
            #pragma unroll
            for (int x = 0; x < 12; ++x) r[x] = row[x];
            #pragma unroll
            for (int j = 0; j < 5; ++j) {
                float kv = kc1[di * 5 + j];
                #pragma unroll
                for (int e = 0; e < 8; ++e) a1[e] = fmaf(kv, r[j + e], a1[e]);
            }
            if ((di & 1) == 0) {
                int i2 = di >> 1;
                #pragma unroll
                for (int j = 0; j < 3; ++j) {
                    float kv = kc2[i2 * 3 + j];
                    #pragma unroll
                    for (int e = 0; e < 8; ++e) a2[e] = fmaf(kv, r[2 * j + e], a2[e]);
                }
            }
        }
        int ob = (h * HD + w0) >> 1;
        #pragma unroll
        for (int e = 0; e < 4; ++e) {
            o1p[ob + e] = (u32)f2b(a1[2 * e]) | ((u32)f2b(a1[2 * e + 1]) << 16);
            o2p[ob + e] = (u32)f2b(a2[2 * e]) | ((u32)f2b(a2[2 * e + 1]) << 16);
        }
    }
}

// ---------------- kernel 5: fuse GEMM, 256m x 64hw per block, K=128 staged once ----------------
// Swapped-operand MFMA: A = o-tile (hw is M-dim), B = W_fuse (m is N-dim).
// Lane holds 4 contiguous hw per acc -> f32x4 output stores. HW = 49*64 -> no bounds checks.
// NOTE: b_fuse is [P2] and shared by BOTH branches -> bias[m], never bias[ch_off+m].
#define FSTR 140   // u16 stride per col
__global__ __launch_bounds__(256) void fuse_kernel(
    const u16* __restrict__ o1, const u16* __restrict__ o2,
    const u16* __restrict__ Wfb, const float* __restrict__ bias,
    float* __restrict__ out)
{
    __shared__ u16 ldsT[64 * FSTR];   // [col 64][k 128], transposed

    const int n   = blockIdx.z;
    const int br  = blockIdx.y;
    const u16* In = br ? o2 : o1;
    const int ch_off = br ? P2 : 0;
    const int hw0 = blockIdx.x * 64;
    const int tid = threadIdx.x;
    const int wave = tid >> 6, lane = tid & 63;
    const int wm  = wave * 64;           // wave m-offset (4 waves cover m 0..255)
    const int qa  = lane >> 4, l15 = lane & 15;

    // stage o tile: [64 cols][128 k]; thread -> 2 k-rows x 8 cols, 2 phases
    {
        const int c0 = (tid & 7) * 8;
        const int kp = tid >> 3;         // 0..31
        #pragma unroll
        for (int kk = 0; kk < CM; kk += 64) {
            const u16* p0 = In + (size_t)n * CM * HW + (size_t)(kk + 2 * kp) * HW + hw0 + c0;
            ushort8 v0 = *(const ushort8*)p0;
            ushort8 v1 = *(const ushort8*)(p0 + HW);
            #pragma unroll
            for (int e = 0; e < 8; ++e)
                *(u32*)&ldsT[(c0 + e) * FSTR + kk + 2 * kp] = (u32)v0[e] | ((u32)v1[e] << 16);
        }
    }
    __syncthreads();

    f32x4 acc[4][4] = {};                // [ht(hw)][nt(m)]
    #pragma unroll
    for (int q = 0; q < 4; ++q) {        // K chunks of 32
        short8 b[4];
        #pragma unroll
        for (int nt = 0; nt < 4; ++nt) {
            int row = wm + nt * 16 + l15;
            b[nt] = *(const short8*)(Wfb + (size_t)row * CM + q * 32 + qa * 8);
        }
        #pragma unroll
        for (int ht = 0; ht < 4; ++ht) {
            int c = ht * 16 + l15;
            union { ushort4_t h[2]; short8 v; } au;
            au.h[0] = *(const ushort4_t*)&ldsT[c * FSTR + q * 32 + qa * 8];
            au.h[1] = *(const ushort4_t*)&ldsT[c * FSTR + q * 32 + qa * 8 + 4];
            #pragma unroll
            for (int nt = 0; nt < 4; ++nt)
                acc[ht][nt] = __builtin_amdgcn_mfma_f32_16x16x32_bf16(au.v, b[nt], acc[ht][nt], 0, 0, 0);
        }
    }

    // epilogue: lane holds m = wm+nt*16+l15, hw = hw0+ht*16+qa*4+r -> f32x4 stores
    #pragma unroll
    for (int nt = 0; nt < 4; ++nt) {
        const int m = wm + nt * 16 + l15;
        const float bv = bias[m];        // b_fuse shared across branches (bug fix vs R2)
        float* orow = out + ((size_t)n * 512 + ch_off + m) * HW + hw0 + qa * 4;
        #pragma unroll
        for (int ht = 0; ht < 4; ++ht) {
            f32x4 v;
            v[0] = acc[ht][nt][0] + bv;
            v[1] = acc[ht][nt][1] + bv;
            v[2] = acc[ht][nt][2] + bv;
            v[3] = acc[ht][nt][3] + bv;
            *(f32x4*)(orow + ht * 16) = v;
        }
    }
}

extern "C" void kernel_launch(void* const* d_in, const int* in_sizes, int n_in,
                              void* d_out, int out_size, void* d_ws, size_t ws_size,
                              hipStream_t stream) {
    const float* x     = (const float*)d_in[0];
    const float* Wconv = (const float*)d_in[1];
    const float* bconv = (const float*)d_in[2];
    const float* wk    = (const float*)d_in[3];
    const float* bk    = (const float*)d_in[4];
    const float* wck   = (const float*)d_in[5];
    const float* bck   = (const float*)d_in[6];
    const float* wk2   = (const float*)d_in[7];
    const float* bk2   = (const float*)d_in[8];
    const float* wck2  = (const float*)d_in[9];
    const float* bck2  = (const float*)d_in[10];
    const float* Wfuse = (const float*)d_in[11];
    const float* bfuse = (const float*)d_in[12];
    float* out = (float*)d_out;

    // workspace layout (all regions fully rewritten every call)
    float* ym  = (float*)d_ws;                // NB*CM f32 (zeroed by init)
    u16*   Wcb = (u16*)(ym + NB * CM);        // CM*CIN bf16
    u16*   Wfb = Wcb + CM * CIN;              // P2*CM bf16
    u16*   f   = Wfb + P2 * CM;               // NB*CM*HW bf16
    u16*   o1  = f  + (size_t)NB * CM * HW;   // NB*CM*HW bf16
    u16*   o2  = o1 + (size_t)NB * CM * HW;   // NB*CM*HW bf16

    {
        int tot = CM * CIN + P2 * CM + NB * CM;
        init_kernel<<<dim3((tot + 255) / 256), 256, 0, stream>>>(Wconv, Wfuse, Wcb, Wfb, ym);
    }
    // f = relu(W_conv @ x); ym[n,m] = sum_hw(preact)
    gemm1_kernel<<<dim3(25, 1, NB), 256, 0, stream>>>(x, Wcb, bconv, f, ym);
    // depthwise branches (computes g = relu(ym/HW + b) inline)
    dw_kernel<<<dim3(NB * CM), 256, 0, stream>>>(f, ym, bconv, wk, bk, wck, bck,
                                                 wk2, bk2, wck2, bck2, o1, o2);
    // y1/y2 = W_fuse @ o1/o2 + b_fuse
    fuse_kernel<<<dim3(49, 2, NB), 256, 0, stream>>>(o1, o2, Wfb, bfuse, out);
}

// Round 6
// 446.981 us; speedup vs baseline: 1.0243x; 1.0243x over previous
//
#include <hip/hip_runtime.h>

typedef unsigned short u16;
typedef unsigned int   u32;

#define NB   32
#define CIN  512
#define CM   128
#define P2   256
#define HW   3136
#define HD   56

typedef __attribute__((ext_vector_type(8))) short           short8;
typedef __attribute__((ext_vector_type(8))) unsigned short  ushort8;
typedef __attribute__((ext_vector_type(4))) float           f32x4;
typedef __attribute__((ext_vector_type(2))) unsigned int    u32x2;

__device__ __forceinline__ float b2f(u16 u) {
    union { u32 i; float f; } v; v.i = ((u32)u) << 16; return v.f;
}
__device__ __forceinline__ u16 f2b(float f) {
    u32 u = __builtin_bit_cast(u32, f);
    u32 r = (u + 0x7fffu + ((u >> 16) & 1u)) >> 16;
    return (u16)r;
}

// ---------------- kernel 0: zero ym + convert weights f32 -> bf16 ----------------
__global__ __launch_bounds__(256) void init_kernel(const float* __restrict__ Wc,
                                                   const float* __restrict__ Wf,
                                                   u16* __restrict__ Wcb,
                                                   u16* __restrict__ Wfb,
                                                   float* __restrict__ ym) {
    int i = blockIdx.x * 256 + threadIdx.x;
    if (i < CM * CIN) { Wcb[i] = f2b(Wc[i]); return; }
    i -= CM * CIN;
    if (i < P2 * CM) { Wfb[i] = f2b(Wf[i]); return; }
    i -= P2 * CM;
    if (i < NB * CM) ym[i] = 0.f;
}

// ---------------- kernel 1: f = relu(Wconv @ x); ym[n,m] += sum_hw preact ----------------
// Tile 128m x 64hw, K-step 64, grid 49x32 (HW = 49*64 -> no hw bounds checks).
// LDS [col][k64] stride 72 u16, XOR octet swizzle (o ^= (col>>3)&7) -> 2-way banks on
// both ds_write_b32 staging and ds_read_b128 frag reads. Double-buffered: 1 barrier/K-step.
// Swapped-operand MFMA: A = x-tile (hw = M-dim), B = W (m = N-dim);
// D: col(l15)=m, row(qa*4+r)=hw -> 4 contiguous hw/lane -> 8B packed bf16 stores.
// Epilogue accumulates pre-bias sum_hw into ym (g = relu(ym/HW + b) derived later in dw).
#define G1S 72               // u16 stride per col
__global__ __launch_bounds__(256) void gemm1_kernel(
    const float* __restrict__ In,
    const u16* __restrict__ Wm, const float* __restrict__ bias,
    u16* __restrict__ Out, float* __restrict__ ym)
{
    __shared__ u16 lds[2 * 64 * G1S];    // 18.4 KB double-buffered

    const int n    = blockIdx.y;
    const int hw0  = blockIdx.x * 64;
    const int tid  = threadIdx.x;
    const int wave = tid >> 6, lane = tid & 63;
    const int wm   = (wave >> 1) * 64;   // wave m-offset
    const int wn   = (wave & 1) * 32;    // wave hw-offset
    const int qa   = lane >> 4;          // k-quad 0..3
    const int l15  = lane & 15;

    f32x4 acc[2][4] = {};                // [ht(hw)][nt(m)]

    // staging: thread -> 2 k-rows (2*kp, 2*kp+1) x 8 hw-cols (c0..c0+7)
    const int kp   = tid >> 3;           // 0..31
    const int c0   = (tid & 7) * 8;
    const int sw   = tid & 7;            // = ((c0+e)>>3)&7 for all e<8
    // write offset (u16): col*G1S + ((kp>>2) ^ sw)*8 + 2*(kp&3), col = c0+e
    const int wbase = c0 * G1S + (((kp >> 2) ^ sw) << 3) + 2 * (kp & 3);
    const float* inb = In + (size_t)n * CIN * HW + hw0 + c0;

    // prologue: stage k0 = 0 into buf 0
    {
        const float* p = inb + (size_t)(2 * kp) * HW;
        f32x4 a0 = *(const f32x4*)p;
        f32x4 a1 = *(const f32x4*)(p + 4);
        f32x4 d0 = *(const f32x4*)(p + HW);
        f32x4 d1 = *(const f32x4*)(p + HW + 4);
        float fa[8] = {a0[0],a0[1],a0[2],a0[3],a1[0],a1[1],a1[2],a1[3]};
        float fb[8] = {d0[0],d0[1],d0[2],d0[3],d1[0],d1[1],d1[2],d1[3]};
        #pragma unroll
        for (int e = 0; e < 8; ++e) {
            u32 ua = __builtin_bit_cast(u32, fa[e]) + 0x8000u;
            u32 ub = __builtin_bit_cast(u32, fb[e]) + 0x8000u;
            *(u32*)&lds[wbase + e * G1S] = __builtin_amdgcn_perm(ub, ua, 0x07060302u);
        }
    }
    __syncthreads();

    for (int k0 = 0; k0 < CIN; k0 += 64) {
        u16* cbuf = &lds[((k0 >> 6) & 1) * (64 * G1S)];
        u16* nbuf = &lds[(~(k0 >> 6) & 1) * (64 * G1S)];
        const bool more = (k0 + 64 < CIN);

        // issue next-tile global loads early (latency hides under B-loads + MFMA)
        f32x4 a0, a1, d0, d1;
        if (more) {
            const float* p = inb + (size_t)(k0 + 64 + 2 * kp) * HW;
            a0 = *(const f32x4*)p;
            a1 = *(const f32x4*)(p + 4);
            d0 = *(const f32x4*)(p + HW);
            d1 = *(const f32x4*)(p + HW + 4);
        }

        // B fragments for this K-step (L2-hot)
        short8 b0[4], b1[4];
        #pragma unroll
        for (int nt = 0; nt < 4; ++nt) {
            const u16* wr = Wm + (size_t)(wm + nt * 16 + l15) * CIN + k0 + qa * 8;
            b0[nt] = *(const short8*)wr;
            b1[nt] = *(const short8*)(wr + 32);
        }

        // MFMA from current buffer (octet-swizzled b128 reads)
        #pragma unroll
        for (int ht = 0; ht < 2; ++ht) {
            const int col = wn + ht * 16 + l15;
            const int csz = (col >> 3) & 7;
            const u16* cb = cbuf + col * G1S;
            short8 x0 = *(const short8*)(cb + ((qa ^ csz) << 3));
            short8 x1 = *(const short8*)(cb + (((qa + 4) ^ csz) << 3));
            #pragma unroll
            for (int nt = 0; nt < 4; ++nt) {
                acc[ht][nt] = __builtin_amdgcn_mfma_f32_16x16x32_bf16(x0, b0[nt], acc[ht][nt], 0, 0, 0);
                acc[ht][nt] = __builtin_amdgcn_mfma_f32_16x16x32_bf16(x1, b1[nt], acc[ht][nt], 0, 0, 0);
            }
        }

        // pack + write next buffer (no hazard: nbuf != cbuf)
        if (more) {
            float fa[8] = {a0[0],a0[1],a0[2],a0[3],a1[0],a1[1],a1[2],a1[3]};
            float fb[8] = {d0[0],d0[1],d0[2],d0[3],d1[0],d1[1],d1[2],d1[3]};
            #pragma unroll
            for (int e = 0; e < 8; ++e) {
                u32 ua = __builtin_bit_cast(u32, fa[e]) + 0x8000u;
                u32 ub = __builtin_bit_cast(u32, fb[e]) + 0x8000u;
                *(u32*)&nbuf[wbase + e * G1S] = __builtin_amdgcn_perm(ub, ua, 0x07060302u);
            }
        }
        __syncthreads();
    }

    // epilogue: lane holds m = wm+nt*16+l15, hw = hw0+wn+ht*16+qa*4+r (contiguous)
    #pragma unroll
    for (int nt = 0; nt < 4; ++nt) {
        const int m = wm + nt * 16 + l15;
        const float bv = bias[m];
        float s = 0.f;
        #pragma unroll
        for (int ht = 0; ht < 2; ++ht) {
            f32x4 v = acc[ht][nt];
            s += v[0] + v[1] + v[2] + v[3];           // pre-bias sum for ym
            const int hwb = hw0 + wn + ht * 16;
            float v0 = fmaxf(v[0] + bv, 0.f);
            float v1 = fmaxf(v[1] + bv, 0.f);
            float v2 = fmaxf(v[2] + bv, 0.f);
            float v3 = fmaxf(v[3] + bv, 0.f);
            u32x2 pkv;
            pkv.x = (u32)f2b(v0) | ((u32)f2b(v1) << 16);
            pkv.y = (u32)f2b(v2) | ((u32)f2b(v3) << 16);
            *(u32x2*)(Out + ((size_t)n * CM + m) * HW + hwb + qa * 4) = pkv;
        }
        s += __shfl_xor(s, 16);
        s += __shfl_xor(s, 32);
        if (lane < 16) atomicAdd(&ym[n * CM + m], s);
    }
}

// ---------------- kernel 4: both depthwise branches (g computed inline) ----------------
#define PD 60
__global__ __launch_bounds__(256) void dw_kernel(
    const u16* __restrict__ f, const float* __restrict__ ym,
    const float* __restrict__ bc,
    const float* __restrict__ wk,  const float* __restrict__ bk,
    const float* __restrict__ wck, const float* __restrict__ bck,
    const float* __restrict__ wk2, const float* __restrict__ bk2,
    const float* __restrict__ wck2,const float* __restrict__ bck2,
    u16* __restrict__ o1, u16* __restrict__ o2)
{
    const int ncm = blockIdx.x;
    __shared__ float fpl[PD * PD];          // 14.4 KB, +-2 halo
    __shared__ float kc1[25], kc2[9];

    // phase A: zero only the halo strips (464 elems) + dynamic kernel coefficients
    {
        int t = threadIdx.x;
        if (t < 120) { fpl[t] = 0.f; fpl[58 * PD + t] = 0.f; }          // rows 0-1, 58-59
        else if (t < 232) {
            int u = t - 120;                   // 0..111 -> rows 2..57, 2 sides x 2 cols
            int r = 2 + (u >> 1), c = u & 1;
            fpl[r * PD + c]      = 0.f;        // cols 0,1
            fpl[r * PD + 58 + c] = 0.f;        // cols 58,59
        }
    }
    // g = relu(ym/HW + b_conv)
    const float gv = fmaxf(ym[ncm] * (1.0f / HW) + bc[ncm & (CM - 1)], 0.f);
    if (threadIdx.x < 25) {
        int t = threadIdx.x;
        kc1[t] = (gv * wk[t] + bk[t]) * wck[0] + bck[0];
    } else if (threadIdx.x >= 32 && threadIdx.x < 41) {
        int t = threadIdx.x - 32;
        kc2[t] = (gv * wk2[t] + bk2[t]) * wck2[0] + bck2[0];
    }
    __syncthreads();

    // phase B: fill interior (bf16 -> f32), 8B/lane (4 px; never crosses a row: 56%4==0)
    const size_t base = (size_t)ncm * HW;
    const u32x2* fp = (const u32x2*)(f + base);
    for (int i = threadIdx.x; i < HW / 4; i += 256) {
        u32x2 v = fp[i];
        int px = 4 * i;
        int h = px / HD, w = px - h * HD;   // w multiple of 4, w <= 52
        float* dst = &fpl[(h + 2) * PD + (w + 2)];
        dst[0] = b2f((u16)v.x);
        dst[1] = b2f((u16)(v.x >> 16));
        dst[2] = b2f((u16)v.y);
        dst[3] = b2f((u16)(v.y >> 16));
    }
    __syncthreads();

    // phase C: 8 px per unit; 7 groups x 56 rows = 392 units
    u32* o1p = (u32*)(o1 + base);
    u32* o2p = (u32*)(o2 + base);
    for (int u = threadIdx.x; u < 392; u += 256) {
        int h  = u / 7;
        int gq = u - h * 7;
        int w0 = gq * 8;
        float a1[8] = {}, a2[8] = {};
        #pragma unroll
        for (int di = 0; di < 5; ++di) {
            const float* row = &fpl[(h + di) * PD + w0];
            float r[12];
            #pragma unroll
            for (int x = 0; x < 12; ++x) r[x] = row[x];
            #pragma unroll
            for (int j = 0; j < 5; ++j) {
                float kv = kc1[di * 5 + j];
                #pragma unroll
                for (int e = 0; e < 8; ++e) a1[e] = fmaf(kv, r[j + e], a1[e]);
            }
            if ((di & 1) == 0) {
                int i2 = di >> 1;
                #pragma unroll
                for (int j = 0; j < 3; ++j) {
                    float kv = kc2[i2 * 3 + j];
                    #pragma unroll
                    for (int e = 0; e < 8; ++e) a2[e] = fmaf(kv, r[2 * j + e], a2[e]);
                }
            }
        }
        int ob = (h * HD + w0) >> 1;
        #pragma unroll
        for (int e = 0; e < 4; ++e) {
            o1p[ob + e] = (u32)f2b(a1[2 * e]) | ((u32)f2b(a1[2 * e + 1]) << 16);
            o2p[ob + e] = (u32)f2b(a2[2 * e]) | ((u32)f2b(a2[2 * e + 1]) << 16);
        }
    }
}

// ---------------- kernel 5: fuse GEMM, 256m x 64hw per block, K=128 staged once ----------------
// LDS [col][k128] stride 144 u16 with XOR octet swizzle -> 2-way banks on writes and
// single aligned ds_read_b128 frag reads. b_fuse shared by BOTH branches -> bias[m].
#define FSTR 144   // u16 stride per col
__global__ __launch_bounds__(256) void fuse_kernel(
    const u16* __restrict__ o1, const u16* __restrict__ o2,
    const u16* __restrict__ Wfb, const float* __restrict__ bias,
    float* __restrict__ out)
{
    __shared__ u16 ldsT[64 * FSTR];   // 18.4 KB, [col 64][k 128]

    const int n   = blockIdx.z;
    const int br  = blockIdx.y;
    const u16* In = br ? o2 : o1;
    const int ch_off = br ? P2 : 0;
    const int hw0 = blockIdx.x * 64;
    const int tid = threadIdx.x;
    const int wave = tid >> 6, lane = tid & 63;
    const int wm  = wave * 64;           // wave m-offset (4 waves cover m 0..255)
    const int qa  = lane >> 4, l15 = lane & 15;

    // stage o tile: [64 cols][128 k]; thread -> 2 k-rows x 8 cols, 2 phases
    {
        const int c0 = (tid & 7) * 8;
        const int kp = tid >> 3;         // 0..31
        const int sw = tid & 7;          // = ((c0+e)>>3)&7
        #pragma unroll
        for (int kk = 0; kk < CM; kk += 64) {
            const u16* p0 = In + (size_t)n * CM * HW + (size_t)(kk + 2 * kp) * HW + hw0 + c0;
            ushort8 v0 = *(const ushort8*)p0;
            ushort8 v1 = *(const ushort8*)(p0 + HW);
            const int wb = c0 * FSTR + ((((kk >> 3) + (kp >> 2)) ^ sw) << 3) + 2 * (kp & 3);
            #pragma unroll
            for (int e = 0; e < 8; ++e)
                *(u32*)&ldsT[wb + e * FSTR] = (u32)v0[e] | ((u32)v1[e] << 16);
        }
    }
    __syncthreads();

    f32x4 acc[4][4] = {};                // [ht(hw)][nt(m)]
    #pragma unroll
    for (int q = 0; q < 4; ++q) {        // K chunks of 32
        short8 b[4];
        #pragma unroll
        for (int nt = 0; nt < 4; ++nt) {
            int row = wm + nt * 16 + l15;
            b[nt] = *(const short8*)(Wfb + (size_t)row * CM + q * 32 + qa * 8);
        }
        #pragma unroll
        for (int ht = 0; ht < 4; ++ht) {
            const int col = ht * 16 + l15;
            const int csz = (col >> 3) & 7;
            short8 av = *(const short8*)&ldsT[col * FSTR + (((q * 4 + qa) ^ csz) << 3)];
            #pragma unroll
            for (int nt = 0; nt < 4; ++nt)
                acc[ht][nt] = __builtin_amdgcn_mfma_f32_16x16x32_bf16(av, b[nt], acc[ht][nt], 0, 0, 0);
        }
    }

    // epilogue: lane holds m = wm+nt*16+l15, hw = hw0+ht*16+qa*4+r -> f32x4 stores
    #pragma unroll
    for (int nt = 0; nt < 4; ++nt) {
        const int m = wm + nt * 16 + l15;
        const float bv = bias[m];        // b_fuse shared across branches
        float* orow = out + ((size_t)n * 512 + ch_off + m) * HW + hw0 + qa * 4;
        #pragma unroll
        for (int ht = 0; ht < 4; ++ht) {
            f32x4 v;
            v[0] = acc[ht][nt][0] + bv;
            v[1] = acc[ht][nt][1] + bv;
            v[2] = acc[ht][nt][2] + bv;
            v[3] = acc[ht][nt][3] + bv;
            *(f32x4*)(orow + ht * 16) = v;
        }
    }
}

extern "C" void kernel_launch(void* const* d_in, const int* in_sizes, int n_in,
                              void* d_out, int out_size, void* d_ws, size_t ws_size,
                              hipStream_t stream) {
    const float* x     = (const float*)d_in[0];
    const float* Wconv = (const float*)d_in[1];
    const float* bconv = (const float*)d_in[2];
    const float* wk    = (const float*)d_in[3];
    const float* bk    = (const float*)d_in[4];
    const float* wck   = (const float*)d_in[5];
    const float* bck   = (const float*)d_in[6];
    const float* wk2   = (const float*)d_in[7];
    const float* bk2   = (const float*)d_in[8];
    const float* wck2  = (const float*)d_in[9];
    const float* bck2  = (const float*)d_in[10];
    const float* Wfuse = (const float*)d_in[11];
    const float* bfuse = (const float*)d_in[12];
    float* out = (float*)d_out;

    // workspace layout (all regions fully rewritten every call)
    float* ym  = (float*)d_ws;                // NB*CM f32 (zeroed by init)
    u16*   Wcb = (u16*)(ym + NB * CM);        // CM*CIN bf16
    u16*   Wfb = Wcb + CM * CIN;              // P2*CM bf16
    u16*   f   = Wfb + P2 * CM;               // NB*CM*HW bf16
    u16*   o1  = f  + (size_t)NB * CM * HW;   // NB*CM*HW bf16
    u16*   o2  = o1 + (size_t)NB * CM * HW;   // NB*CM*HW bf16

    {
        int tot = CM * CIN + P2 * CM + NB * CM;
        init_kernel<<<dim3((tot + 255) / 256), 256, 0, stream>>>(Wconv, Wfuse, Wcb, Wfb, ym);
    }
    // f = relu(W_conv @ x); ym[n,m] = sum_hw(preact)
    gemm1_kernel<<<dim3(49, NB), 256, 0, stream>>>(x, Wcb, bconv, f, ym);
    // depthwise branches (computes g = relu(ym/HW + b) inline)
    dw_kernel<<<dim3(NB * CM), 256, 0, stream>>>(f, ym, bconv, wk, bk, wck, bck,
                                                 wk2, bk2, wck2, bck2, o1, o2);
    // y1/y2 = W_fuse @ o1/o2 + b_fuse
    fuse_kernel<<<dim3(49, 2, NB), 256, 0, stream>>>(o1, o2, Wfb, bfuse, out);
}